// Round 1
// baseline (5998.748 us; speedup 1.0000x reference)
//
#include <hip/hip_runtime.h>
#include <hip/hip_bf16.h>

#define N_NODES_C 50000
#define N_EDGES_C 800000

// ---------------------------------------------------------------------------
// K1: scatter-add messages into per-dst-node sums + counts.
// One wavefront (64 lanes) per edge; lane<32 covers nfeats[u] (k=0..127),
// lane>=32 covers efeats[e] (k=128..255). dst offset = lane*4 uniformly.
// ---------------------------------------------------------------------------
__global__ __launch_bounds__(256) void scatter_k(
    const float* __restrict__ nfeats, const float* __restrict__ efeats,
    const int* __restrict__ u, const int* __restrict__ v,
    float* __restrict__ sums, float* __restrict__ counts)
{
    int gtid = blockIdx.x * 256 + threadIdx.x;
    int e    = gtid >> 6;
    int lane = threadIdx.x & 63;
    if (e >= N_EDGES_C) return;
    int uu = u[e], vv = v[e];
    const float* src = (lane < 32)
        ? (nfeats + (size_t)uu * 128 + lane * 4)
        : (efeats + (size_t)e  * 128 + (lane - 32) * 4);
    float4 val = *reinterpret_cast<const float4*>(src);
    float* dst = sums + (size_t)vv * 256 + lane * 4;
    unsafeAtomicAdd(dst + 0, val.x);
    unsafeAtomicAdd(dst + 1, val.y);
    unsafeAtomicAdd(dst + 2, val.z);
    unsafeAtomicAdd(dst + 3, val.w);
    if (lane == 0) unsafeAtomicAdd(counts + vv, 1.0f);
}

// ---------------------------------------------------------------------------
// Shared GEMM tile: C[32 rows x 128 outs] = relu(Xs^T @ W^T + b)
// Xs is LDS [K][32] (k-major). W is [128][K] row-major (original layout).
// 256 threads: colg=tid&31 -> outs o0=colg*4; rowg=tid>>5 -> rows e0=rowg*4.
// Per k-quad: 4x ds_read_b128 (banks rowg*4..+3, conflict-free) +
// 4x global float4 from W rows (L2-hot), 64 FMA.
// ---------------------------------------------------------------------------
template <int K>
__device__ __forceinline__ void tile_gemm_relu_store(
    const float (*__restrict__ Xs)[32],
    const float* __restrict__ W, const float* __restrict__ bias,
    float* __restrict__ out, int row0, int row_limit)
{
    int tid = threadIdx.x;
    int o0 = (tid & 31) * 4;
    int e0 = (tid >> 5) * 4;

    float acc[4][4];
#pragma unroll
    for (int i = 0; i < 4; ++i)
#pragma unroll
        for (int j = 0; j < 4; ++j) acc[i][j] = 0.f;

    const float* W0 = W + (size_t)(o0 + 0) * K;
    const float* W1 = W + (size_t)(o0 + 1) * K;
    const float* W2 = W + (size_t)(o0 + 2) * K;
    const float* W3 = W + (size_t)(o0 + 3) * K;

#pragma unroll 2
    for (int k = 0; k < K; k += 4) {
        float4 xa = *reinterpret_cast<const float4*>(&Xs[k + 0][e0]);
        float4 xb = *reinterpret_cast<const float4*>(&Xs[k + 1][e0]);
        float4 xc = *reinterpret_cast<const float4*>(&Xs[k + 2][e0]);
        float4 xd = *reinterpret_cast<const float4*>(&Xs[k + 3][e0]);
        float4 w0 = *reinterpret_cast<const float4*>(W0 + k);
        float4 w1 = *reinterpret_cast<const float4*>(W1 + k);
        float4 w2 = *reinterpret_cast<const float4*>(W2 + k);
        float4 w3 = *reinterpret_cast<const float4*>(W3 + k);

        const float xj[4][4] = {
            {xa.x, xa.y, xa.z, xa.w},
            {xb.x, xb.y, xb.z, xb.w},
            {xc.x, xc.y, xc.z, xc.w},
            {xd.x, xd.y, xd.z, xd.w}};
        const float wj[4][4] = {
            {w0.x, w0.y, w0.z, w0.w},
            {w1.x, w1.y, w1.z, w1.w},
            {w2.x, w2.y, w2.z, w2.w},
            {w3.x, w3.y, w3.z, w3.w}};
#pragma unroll
        for (int oi = 0; oi < 4; ++oi)
#pragma unroll
            for (int j = 0; j < 4; ++j)
#pragma unroll
                for (int ei = 0; ei < 4; ++ei)
                    acc[ei][oi] = fmaf(xj[j][ei], wj[oi][j], acc[ei][oi]);
    }

    float4 bv = *reinterpret_cast<const float4*>(bias + o0);
    const float bvv[4] = {bv.x, bv.y, bv.z, bv.w};
#pragma unroll
    for (int ei = 0; ei < 4; ++ei) {
        int r = row0 + e0 + ei;
        if (r < row_limit) {
            float4 ov;
            ov.x = fmaxf(acc[ei][0] + bvv[0], 0.f);
            ov.y = fmaxf(acc[ei][1] + bvv[1], 0.f);
            ov.z = fmaxf(acc[ei][2] + bvv[2], 0.f);
            ov.w = fmaxf(acc[ei][3] + bvv[3], 0.f);
            *reinterpret_cast<float4*>(out + (size_t)r * 128 + o0) = ov;
        }
    }
}

// ---------------------------------------------------------------------------
// K2: node update. x = concat(nfeats[n] (128), sums[n]*rinv (256)), K=384.
// ---------------------------------------------------------------------------
__global__ __launch_bounds__(256) void node_k(
    const float* __restrict__ nfeats, const float* __restrict__ sums,
    const float* __restrict__ counts, const float* __restrict__ W,
    const float* __restrict__ bias, float* __restrict__ out)
{
    __shared__ float Xs[384][32];
    __shared__ float rinv[32];
    int tid = threadIdx.x;
    int n0  = blockIdx.x * 32;

    if (tid < 32) {
        int n = n0 + tid;
        float c = (n < N_NODES_C) ? counts[n] : 0.f;
        rinv[tid] = (c > 0.f) ? 1.f / c : 0.f;
    }
    __syncthreads();

    {
        int e = tid & 31;
        int n = n0 + e;
        bool valid = (n < N_NODES_C);
#pragma unroll
        for (int pass = 0; pass < 12; ++pass) {
            int kc = (tid >> 5) + pass * 8;   // 0..95
            int k  = kc * 4;
            float4 val = make_float4(0.f, 0.f, 0.f, 0.f);
            if (valid) {
                if (k < 128) {
                    val = *reinterpret_cast<const float4*>(nfeats + (size_t)n * 128 + k);
                } else {
                    val = *reinterpret_cast<const float4*>(sums + (size_t)n * 256 + (k - 128));
                    float r = rinv[e];
                    val.x *= r; val.y *= r; val.z *= r; val.w *= r;
                }
            }
            Xs[k + 0][e] = val.x;
            Xs[k + 1][e] = val.y;
            Xs[k + 2][e] = val.z;
            Xs[k + 3][e] = val.w;
        }
    }
    __syncthreads();

    tile_gemm_relu_store<384>(Xs, W, bias, out, n0, N_NODES_C);
}

// ---------------------------------------------------------------------------
// K3: edge update. x = concat(h[u[e]] (128), h[v[e]] (128)), K=256.
// ---------------------------------------------------------------------------
__global__ __launch_bounds__(256) void edge_k(
    const float* __restrict__ h, const int* __restrict__ u,
    const int* __restrict__ v, const float* __restrict__ W,
    const float* __restrict__ bias, float* __restrict__ out)
{
    __shared__ float Xs[256][32];
    __shared__ int us[32], vs[32];
    int tid = threadIdx.x;
    int e0b = blockIdx.x * 32;

    if (tid < 32)       us[tid]      = u[e0b + tid];
    else if (tid < 64)  vs[tid - 32] = v[e0b + (tid - 32)];
    __syncthreads();

    {
        int e = tid & 31;
#pragma unroll
        for (int pass = 0; pass < 8; ++pass) {
            int kc = (tid >> 5) + pass * 8;   // 0..63
            int k  = kc * 4;
            const float* src = (k < 128)
                ? (h + (size_t)us[e] * 128 + k)
                : (h + (size_t)vs[e] * 128 + (k - 128));
            float4 val = *reinterpret_cast<const float4*>(src);
            Xs[k + 0][e] = val.x;
            Xs[k + 1][e] = val.y;
            Xs[k + 2][e] = val.z;
            Xs[k + 3][e] = val.w;
        }
    }
    __syncthreads();

    tile_gemm_relu_store<256>(Xs, W, bias, out, e0b, N_EDGES_C);
}

// ---------------------------------------------------------------------------
extern "C" void kernel_launch(void* const* d_in, const int* in_sizes, int n_in,
                              void* d_out, int out_size, void* d_ws, size_t ws_size,
                              hipStream_t stream)
{
    const float* nfeats    = (const float*)d_in[0];
    const float* efeats    = (const float*)d_in[1];
    const int*   u         = (const int*)d_in[2];
    const int*   v         = (const int*)d_in[3];
    const float* W_apply_w = (const float*)d_in[4];
    const float* W_apply_b = (const float*)d_in[5];
    const float* W_edge_w  = (const float*)d_in[6];
    const float* W_edge_b  = (const float*)d_in[7];

    float* out      = (float*)d_out;
    float* h_nodes  = out;                                // [50000][128]
    float* edge_out = out + (size_t)N_NODES_C * 128;      // [800000][128]

    // Scratch overlays the edge-output region (409.6 MB >> 51.4 MB needed).
    // Safe: edge_k (which overwrites this region) runs after node_k has
    // consumed sums/counts, and edge_k itself reads only h_nodes + inputs.
    float* sums   = edge_out;                             // [50000][256]
    float* counts = sums + (size_t)N_NODES_C * 256;       // [50000]

    hipMemsetAsync(sums, 0,
                   ((size_t)N_NODES_C * 256 + N_NODES_C) * sizeof(float),
                   stream);

    scatter_k<<<N_EDGES_C / 4, 256, 0, stream>>>(nfeats, efeats, u, v, sums, counts);

    node_k<<<(N_NODES_C + 31) / 32, 256, 0, stream>>>(
        nfeats, sums, counts, W_apply_w, W_apply_b, h_nodes);

    edge_k<<<N_EDGES_C / 32, 256, 0, stream>>>(
        h_nodes, u, v, W_edge_w, W_edge_b, edge_out);
}

// Round 2
// 1005.351 us; speedup vs baseline: 5.9668x; 5.9668x over previous
//
#include <hip/hip_runtime.h>
#include <hip/hip_bf16.h>

#define N_NODES_C 50000
#define N_EDGES_C 800000

typedef __attribute__((ext_vector_type(8))) short bf16x8;
typedef __attribute__((ext_vector_type(4))) float f32x4;

__device__ __forceinline__ unsigned short f2bf(float f) {
    unsigned int x = __float_as_uint(f);
    unsigned int r = x + 0x7fffu + ((x >> 16) & 1u);   // RNE
    return (unsigned short)(r >> 16);
}

// ---------------------------------------------------------------------------
// CSR build: count -> scan -> fill
// ---------------------------------------------------------------------------
__global__ __launch_bounds__(256) void count_k(const int* __restrict__ v, int* __restrict__ cnt)
{
    int e = blockIdx.x * 256 + threadIdx.x;   // grid sized exactly
    atomicAdd(&cnt[v[e]], 1);
}

__global__ __launch_bounds__(1024) void scan_k(const int* __restrict__ cnt,
                                               int* __restrict__ rowst,
                                               int* __restrict__ cursor)
{
    __shared__ int wsum[16];
    int tid = threadIdx.x, lane = tid & 63, wid = tid >> 6;
    int carry = 0;
    for (int base = 0; base < N_NODES_C; base += 1024) {
        int i = base + tid;
        int x = (i < N_NODES_C) ? cnt[i] : 0;
        int s = x;
#pragma unroll
        for (int d = 1; d < 64; d <<= 1) {
            int t = __shfl_up(s, d, 64);
            if (lane >= d) s += t;
        }
        if (lane == 63) wsum[wid] = s;
        __syncthreads();
        if (wid == 0) {
            int w = (lane < 16) ? wsum[lane] : 0;
#pragma unroll
            for (int d = 1; d < 16; d <<= 1) {
                int t = __shfl_up(w, d, 64);
                if (lane >= d) w += t;
            }
            if (lane < 16) wsum[lane] = w;
        }
        __syncthreads();
        int offset = carry + (wid > 0 ? wsum[wid - 1] : 0);
        int excl = offset + s - x;
        if (i < N_NODES_C) { rowst[i] = excl; cursor[i] = excl; }
        carry += wsum[15];
        __syncthreads();
    }
    if (tid == 0) rowst[N_NODES_C] = carry;
}

__global__ __launch_bounds__(256) void fill_k(const int* __restrict__ v,
                                              int* __restrict__ cursor,
                                              int* __restrict__ eids)
{
    int e = blockIdx.x * 256 + threadIdx.x;
    int pos = atomicAdd(&cursor[v[e]], 1);
    eids[pos] = e;
}

// ---------------------------------------------------------------------------
// Aggregate: one block per dst node; thread t owns feature dim t (0..255).
// msg = concat(nfeats[u[e]] (128), efeats[e] (128)); mean over edge list.
// ---------------------------------------------------------------------------
__global__ __launch_bounds__(256) void aggregate_k(
    const int* __restrict__ u, const int* __restrict__ eids,
    const int* __restrict__ rowst,
    const float* __restrict__ nfeats, const float* __restrict__ efeats,
    float* __restrict__ h_neigh)
{
    int n = blockIdx.x, tid = threadIdx.x;
    int s = rowst[n], epos_end = rowst[n + 1];
    float acc = 0.f;
    for (int i = s; i < epos_end; ++i) {
        int e = eids[i];
        float val;
        if (tid < 128) {
            int uu = u[e];
            val = nfeats[(size_t)uu * 128 + tid];
        } else {
            val = efeats[(size_t)e * 128 + tid - 128];
        }
        acc += val;
    }
    int deg = epos_end - s;
    h_neigh[(size_t)n * 256 + tid] = (deg > 0) ? acc / (float)deg : 0.f;
}

// ---------------------------------------------------------------------------
// fp32 GEMM tile for node update (kept fp32 for output-0 accuracy).
// C[32 rows x 128 outs] = relu(Xs^T @ W^T + b), Xs LDS [K][32] k-major.
// ---------------------------------------------------------------------------
template <int K>
__device__ __forceinline__ void tile_gemm_relu_store(
    const float (*__restrict__ Xs)[32],
    const float* __restrict__ W, const float* __restrict__ bias,
    float* __restrict__ out, int row0, int row_limit)
{
    int tid = threadIdx.x;
    int o0 = (tid & 31) * 4;
    int e0 = (tid >> 5) * 4;

    float acc[4][4];
#pragma unroll
    for (int i = 0; i < 4; ++i)
#pragma unroll
        for (int j = 0; j < 4; ++j) acc[i][j] = 0.f;

    const float* W0 = W + (size_t)(o0 + 0) * K;
    const float* W1 = W + (size_t)(o0 + 1) * K;
    const float* W2 = W + (size_t)(o0 + 2) * K;
    const float* W3 = W + (size_t)(o0 + 3) * K;

#pragma unroll 2
    for (int k = 0; k < K; k += 4) {
        float4 xa = *reinterpret_cast<const float4*>(&Xs[k + 0][e0]);
        float4 xb = *reinterpret_cast<const float4*>(&Xs[k + 1][e0]);
        float4 xc = *reinterpret_cast<const float4*>(&Xs[k + 2][e0]);
        float4 xd = *reinterpret_cast<const float4*>(&Xs[k + 3][e0]);
        float4 w0 = *reinterpret_cast<const float4*>(W0 + k);
        float4 w1 = *reinterpret_cast<const float4*>(W1 + k);
        float4 w2 = *reinterpret_cast<const float4*>(W2 + k);
        float4 w3 = *reinterpret_cast<const float4*>(W3 + k);

        const float xj[4][4] = {
            {xa.x, xa.y, xa.z, xa.w},
            {xb.x, xb.y, xb.z, xb.w},
            {xc.x, xc.y, xc.z, xc.w},
            {xd.x, xd.y, xd.z, xd.w}};
        const float wj[4][4] = {
            {w0.x, w0.y, w0.z, w0.w},
            {w1.x, w1.y, w1.z, w1.w},
            {w2.x, w2.y, w2.z, w2.w},
            {w3.x, w3.y, w3.z, w3.w}};
#pragma unroll
        for (int oi = 0; oi < 4; ++oi)
#pragma unroll
            for (int j = 0; j < 4; ++j)
#pragma unroll
                for (int ei = 0; ei < 4; ++ei)
                    acc[ei][oi] = fmaf(xj[j][ei], wj[oi][j], acc[ei][oi]);
    }

    float4 bv = *reinterpret_cast<const float4*>(bias + o0);
    const float bvv[4] = {bv.x, bv.y, bv.z, bv.w};
#pragma unroll
    for (int ei = 0; ei < 4; ++ei) {
        int r = row0 + e0 + ei;
        if (r < row_limit) {
            float4 ov;
            ov.x = fmaxf(acc[ei][0] + bvv[0], 0.f);
            ov.y = fmaxf(acc[ei][1] + bvv[1], 0.f);
            ov.z = fmaxf(acc[ei][2] + bvv[2], 0.f);
            ov.w = fmaxf(acc[ei][3] + bvv[3], 0.f);
            *reinterpret_cast<float4*>(out + (size_t)r * 128 + o0) = ov;
        }
    }
}

// ---------------------------------------------------------------------------
// K2: node update. x = concat(nfeats[n] (128), h_neigh[n] (256)), K=384.
// ---------------------------------------------------------------------------
__global__ __launch_bounds__(256) void node_k(
    const float* __restrict__ nfeats, const float* __restrict__ h_neigh,
    const float* __restrict__ W, const float* __restrict__ bias,
    float* __restrict__ out)
{
    __shared__ float Xs[384][32];
    int tid = threadIdx.x;
    int n0  = blockIdx.x * 32;

    {
        int e = tid & 31;
        int n = n0 + e;
        bool valid = (n < N_NODES_C);
#pragma unroll
        for (int pass = 0; pass < 12; ++pass) {
            int kc = (tid >> 5) + pass * 8;   // 0..95
            int k  = kc * 4;
            float4 val = make_float4(0.f, 0.f, 0.f, 0.f);
            if (valid) {
                if (k < 128)
                    val = *reinterpret_cast<const float4*>(nfeats + (size_t)n * 128 + k);
                else
                    val = *reinterpret_cast<const float4*>(h_neigh + (size_t)n * 256 + (k - 128));
            }
            Xs[k + 0][e] = val.x;
            Xs[k + 1][e] = val.y;
            Xs[k + 2][e] = val.z;
            Xs[k + 3][e] = val.w;
        }
    }
    __syncthreads();

    tile_gemm_relu_store<384>(Xs, W, bias, out, n0, N_NODES_C);
}

// ---------------------------------------------------------------------------
// K3: edge update via bf16 MFMA. C[128 e x 128 n] = relu(X @ W^T + b),
// X = concat(h[u],h[v]) gathered+converted to bf16 in staging. BK=64.
// LDS tiles XOR-swizzled: byte ^= (row&7)<<4 (row stride 128B -> G4 fix).
// ---------------------------------------------------------------------------
__device__ __forceinline__ void stage_half_row(
    const float* __restrict__ src, char* __restrict__ lds, int row, int halfg)
{
#pragma unroll
    for (int g = 0; g < 4; ++g) {
        float4 f0 = reinterpret_cast<const float4*>(src)[g * 2 + 0];
        float4 f1 = reinterpret_cast<const float4*>(src)[g * 2 + 1];
        union { unsigned short s[8]; uint4 q; } pk;
        pk.s[0] = f2bf(f0.x); pk.s[1] = f2bf(f0.y);
        pk.s[2] = f2bf(f0.z); pk.s[3] = f2bf(f0.w);
        pk.s[4] = f2bf(f1.x); pk.s[5] = f2bf(f1.y);
        pk.s[6] = f2bf(f1.z); pk.s[7] = f2bf(f1.w);
        int byteoff = ((halfg * 4 + g) * 16) ^ ((row & 7) << 4);
        *reinterpret_cast<uint4*>(lds + row * 128 + byteoff) = pk.q;
    }
}

__global__ __launch_bounds__(256) void edge_k(
    const float* __restrict__ h, const int* __restrict__ u,
    const int* __restrict__ v, const float* __restrict__ W,
    const float* __restrict__ bias, float* __restrict__ out)
{
    __shared__ uint4 XsBuf[1024];   // 16 KB : X tile [128 rows][64 k] bf16, swizzled
    __shared__ uint4 WsBuf[1024];   // 16 KB : W tile [128 out][64 k] bf16, swizzled
    __shared__ int us[128], vs[128];
    char* Xs = (char*)XsBuf;
    char* Ws = (char*)WsBuf;

    int tid = threadIdx.x;
    int e0  = blockIdx.x * 128;
    if (tid < 128) us[tid]       = u[e0 + tid];
    else           vs[tid - 128] = v[e0 + tid - 128];
    __syncthreads();

    int wave = tid >> 6, lane = tid & 63;
    int wm = wave >> 1, wn = wave & 1;
    int srow = tid >> 1, shalf = tid & 1;

    f32x4 acc[4][4];
#pragma unroll
    for (int i = 0; i < 4; ++i)
#pragma unroll
        for (int j = 0; j < 4; ++j) acc[i][j] = (f32x4)0.f;

    for (int k0 = 0; k0 < 256; k0 += 64) {
        // ---- stage X (gather h rows, fp32->bf16) and W ----
        {
            int node = (k0 < 128) ? us[srow] : vs[srow];
            const float* xsrc = h + (size_t)node * 128 + (k0 & 127) + shalf * 32;
            stage_half_row(xsrc, Xs, srow, shalf);
            const float* wsrc = W + (size_t)srow * 256 + k0 + shalf * 32;
            stage_half_row(wsrc, Ws, srow, shalf);
        }
        __syncthreads();

        // ---- MFMA: 2 k-chunks of 32 ----
#pragma unroll
        for (int c = 0; c < 2; ++c) {
            int kb = c * 64 + (lane >> 4) * 16;   // byte offset in row
            bf16x8 a[4], b[4];
#pragma unroll
            for (int i = 0; i < 4; ++i) {
                int row = wm * 64 + i * 16 + (lane & 15);
                a[i] = *reinterpret_cast<const bf16x8*>(
                    Xs + row * 128 + (kb ^ ((row & 7) << 4)));
            }
#pragma unroll
            for (int j = 0; j < 4; ++j) {
                int row = wn * 64 + j * 16 + (lane & 15);
                b[j] = *reinterpret_cast<const bf16x8*>(
                    Ws + row * 128 + (kb ^ ((row & 7) << 4)));
            }
#pragma unroll
            for (int i = 0; i < 4; ++i)
#pragma unroll
                for (int j = 0; j < 4; ++j)
                    acc[i][j] = __builtin_amdgcn_mfma_f32_16x16x32_bf16(
                        a[i], b[j], acc[i][j], 0, 0, 0);
        }
        __syncthreads();
    }

    // ---- epilogue: bias + relu + store (C/D: col=lane&15, row=(lane>>4)*4+r) ----
    int col0 = wn * 64 + (lane & 15);
    int row0 = e0 + wm * 64 + (lane >> 4) * 4;
#pragma unroll
    for (int j = 0; j < 4; ++j) {
        float bj = bias[col0 + j * 16];
#pragma unroll
        for (int i = 0; i < 4; ++i) {
#pragma unroll
            for (int r = 0; r < 4; ++r) {
                float val = fmaxf(acc[i][j][r] + bj, 0.f);
                out[(size_t)(row0 + i * 16 + r) * 128 + col0 + j * 16] = val;
            }
        }
    }
}

// ---------------------------------------------------------------------------
extern "C" void kernel_launch(void* const* d_in, const int* in_sizes, int n_in,
                              void* d_out, int out_size, void* d_ws, size_t ws_size,
                              hipStream_t stream)
{
    const float* nfeats    = (const float*)d_in[0];
    const float* efeats    = (const float*)d_in[1];
    const int*   u         = (const int*)d_in[2];
    const int*   v         = (const int*)d_in[3];
    const float* W_apply_w = (const float*)d_in[4];
    const float* W_apply_b = (const float*)d_in[5];
    const float* W_edge_w  = (const float*)d_in[6];
    const float* W_edge_b  = (const float*)d_in[7];

    float* out      = (float*)d_out;
    float* h_nodes  = out;                                // [50000][128]
    float* edge_out = out + (size_t)N_NODES_C * 128;      // [800000][128]

    // Scratch overlays the edge-output region (409.6 MB; we use ~55 MB).
    // All scratch consumers finish before edge_k overwrites the region.
    float* scratch = edge_out;
    float* h_neigh = scratch;                              // 12.8M floats
    int*   cnt     = (int*)(scratch + 12800000);           // 50000
    int*   rowst   = cnt + N_NODES_C;                      // 50001
    int*   cursor  = rowst + N_NODES_C + 1;                // 50000
    int*   eids    = cursor + N_NODES_C;                   // 800000

    hipMemsetAsync(cnt, 0, N_NODES_C * sizeof(int), stream);

    count_k<<<N_EDGES_C / 256, 256, 0, stream>>>(v, cnt);
    scan_k<<<1, 1024, 0, stream>>>(cnt, rowst, cursor);
    fill_k<<<N_EDGES_C / 256, 256, 0, stream>>>(v, cursor, eids);
    aggregate_k<<<N_NODES_C, 256, 0, stream>>>(u, eids, rowst, nfeats, efeats, h_neigh);

    node_k<<<(N_NODES_C + 31) / 32, 256, 0, stream>>>(
        nfeats, h_neigh, W_apply_w, W_apply_b, h_nodes);

    edge_k<<<N_EDGES_C / 128, 256, 0, stream>>>(
        h_nodes, u, v, W_edge_w, W_edge_b, edge_out);
}

// Round 3
// 902.556 us; speedup vs baseline: 6.6464x; 1.1139x over previous
//
#include <hip/hip_runtime.h>
#include <hip/hip_bf16.h>

#define N_NODES_C 50000
#define N_EDGES_C 800000

typedef __attribute__((ext_vector_type(8))) short bf16x8;
typedef __attribute__((ext_vector_type(4))) float f32x4;

__device__ __forceinline__ unsigned short f2bf(float f) {
    unsigned int x = __float_as_uint(f);
    unsigned int r = x + 0x7fffu + ((x >> 16) & 1u);   // RNE
    return (unsigned short)(r >> 16);
}

// ---------------------------------------------------------------------------
// CSR build: count -> scan -> fill (fill stores (edge_id, u[edge]) pairs to
// remove the eids->u dependent-load chain in aggregation).
// ---------------------------------------------------------------------------
__global__ __launch_bounds__(256) void count_k(const int* __restrict__ v, int* __restrict__ cnt)
{
    int e = blockIdx.x * 256 + threadIdx.x;   // grid sized exactly
    atomicAdd(&cnt[v[e]], 1);
}

__global__ __launch_bounds__(1024) void scan_k(const int* __restrict__ cnt,
                                               int* __restrict__ rowst,
                                               int* __restrict__ cursor)
{
    __shared__ int wsum[16];
    int tid = threadIdx.x, lane = tid & 63, wid = tid >> 6;
    int carry = 0;
    for (int base = 0; base < N_NODES_C; base += 1024) {
        int i = base + tid;
        int x = (i < N_NODES_C) ? cnt[i] : 0;
        int s = x;
#pragma unroll
        for (int d = 1; d < 64; d <<= 1) {
            int t = __shfl_up(s, d, 64);
            if (lane >= d) s += t;
        }
        if (lane == 63) wsum[wid] = s;
        __syncthreads();
        if (wid == 0) {
            int w = (lane < 16) ? wsum[lane] : 0;
#pragma unroll
            for (int d = 1; d < 16; d <<= 1) {
                int t = __shfl_up(w, d, 64);
                if (lane >= d) w += t;
            }
            if (lane < 16) wsum[lane] = w;
        }
        __syncthreads();
        int offset = carry + (wid > 0 ? wsum[wid - 1] : 0);
        int excl = offset + s - x;
        if (i < N_NODES_C) { rowst[i] = excl; cursor[i] = excl; }
        carry += wsum[15];
        __syncthreads();
    }
    if (tid == 0) rowst[N_NODES_C] = carry;
}

__global__ __launch_bounds__(256) void fill_k(const int* __restrict__ v,
                                              const int* __restrict__ u,
                                              int* __restrict__ cursor,
                                              int2* __restrict__ pairs)
{
    int e = blockIdx.x * 256 + threadIdx.x;
    int pos = atomicAdd(&cursor[v[e]], 1);
    pairs[pos] = make_int2(e, u[e]);
}

// ---------------------------------------------------------------------------
// Aggregate: one block per dst node. 4 edge-groups of 64 lanes each process
// 4 edges per iteration; each lane loads one float4 (lane<32 -> nfeats[u],
// lane>=32 -> efeats[e]). Cross-group reduce in LDS, mean, store.
// ---------------------------------------------------------------------------
__global__ __launch_bounds__(256) void aggregate_k(
    const int2* __restrict__ pairs, const int* __restrict__ rowst,
    const float* __restrict__ nfeats, const float* __restrict__ efeats,
    float* __restrict__ h_neigh)
{
    __shared__ float4 red[256];
    int n = blockIdx.x, tid = threadIdx.x;
    int grp = tid >> 6, lane = tid & 63;
    int s = rowst[n], e_end = rowst[n + 1];
    int deg = e_end - s;

    float4 acc = make_float4(0.f, 0.f, 0.f, 0.f);
    for (int i = s + grp; i < e_end; i += 4) {
        int2 p = pairs[i];                  // (edge, src node)
        const float* src = (lane < 32)
            ? (nfeats + (size_t)p.y * 128 + lane * 4)
            : (efeats + (size_t)p.x * 128 + (lane - 32) * 4);
        float4 vv = *reinterpret_cast<const float4*>(src);
        acc.x += vv.x; acc.y += vv.y; acc.z += vv.z; acc.w += vv.w;
    }
    red[tid] = acc;
    __syncthreads();
    if (grp == 0) {
        float4 a = red[lane], b = red[64 + lane], c = red[128 + lane], d = red[192 + lane];
        float r = (deg > 0) ? 1.f / (float)deg : 0.f;
        float4 o;
        o.x = (a.x + b.x + c.x + d.x) * r;
        o.y = (a.y + b.y + c.y + d.y) * r;
        o.z = (a.z + b.z + c.z + d.z) * r;
        o.w = (a.w + b.w + c.w + d.w) * r;
        *reinterpret_cast<float4*>(h_neigh + (size_t)n * 256 + lane * 4) = o;
    }
}

// ---------------------------------------------------------------------------
// fp32 GEMM tile for node update (kept fp32 for output-0 accuracy).
// C[32 rows x 128 outs] = relu(Xs^T @ W^T + b), Xs LDS [K][32] k-major.
// ---------------------------------------------------------------------------
template <int K>
__device__ __forceinline__ void tile_gemm_relu_store(
    const float (*__restrict__ Xs)[32],
    const float* __restrict__ W, const float* __restrict__ bias,
    float* __restrict__ out, int row0, int row_limit)
{
    int tid = threadIdx.x;
    int o0 = (tid & 31) * 4;
    int e0 = (tid >> 5) * 4;

    float acc[4][4];
#pragma unroll
    for (int i = 0; i < 4; ++i)
#pragma unroll
        for (int j = 0; j < 4; ++j) acc[i][j] = 0.f;

    const float* W0 = W + (size_t)(o0 + 0) * K;
    const float* W1 = W + (size_t)(o0 + 1) * K;
    const float* W2 = W + (size_t)(o0 + 2) * K;
    const float* W3 = W + (size_t)(o0 + 3) * K;

#pragma unroll 2
    for (int k = 0; k < K; k += 4) {
        float4 xa = *reinterpret_cast<const float4*>(&Xs[k + 0][e0]);
        float4 xb = *reinterpret_cast<const float4*>(&Xs[k + 1][e0]);
        float4 xc = *reinterpret_cast<const float4*>(&Xs[k + 2][e0]);
        float4 xd = *reinterpret_cast<const float4*>(&Xs[k + 3][e0]);
        float4 w0 = *reinterpret_cast<const float4*>(W0 + k);
        float4 w1 = *reinterpret_cast<const float4*>(W1 + k);
        float4 w2 = *reinterpret_cast<const float4*>(W2 + k);
        float4 w3 = *reinterpret_cast<const float4*>(W3 + k);

        const float xj[4][4] = {
            {xa.x, xa.y, xa.z, xa.w},
            {xb.x, xb.y, xb.z, xb.w},
            {xc.x, xc.y, xc.z, xc.w},
            {xd.x, xd.y, xd.z, xd.w}};
        const float wj[4][4] = {
            {w0.x, w0.y, w0.z, w0.w},
            {w1.x, w1.y, w1.z, w1.w},
            {w2.x, w2.y, w2.z, w2.w},
            {w3.x, w3.y, w3.z, w3.w}};
#pragma unroll
        for (int oi = 0; oi < 4; ++oi)
#pragma unroll
            for (int j = 0; j < 4; ++j)
#pragma unroll
                for (int ei = 0; ei < 4; ++ei)
                    acc[ei][oi] = fmaf(xj[j][ei], wj[oi][j], acc[ei][oi]);
    }

    float4 bv = *reinterpret_cast<const float4*>(bias + o0);
    const float bvv[4] = {bv.x, bv.y, bv.z, bv.w};
#pragma unroll
    for (int ei = 0; ei < 4; ++ei) {
        int r = row0 + e0 + ei;
        if (r < row_limit) {
            float4 ov;
            ov.x = fmaxf(acc[ei][0] + bvv[0], 0.f);
            ov.y = fmaxf(acc[ei][1] + bvv[1], 0.f);
            ov.z = fmaxf(acc[ei][2] + bvv[2], 0.f);
            ov.w = fmaxf(acc[ei][3] + bvv[3], 0.f);
            *reinterpret_cast<float4*>(out + (size_t)r * 128 + o0) = ov;
        }
    }
}

// ---------------------------------------------------------------------------
// K2: node update. x = concat(nfeats[n] (128), h_neigh[n] (256)), K=384.
// ---------------------------------------------------------------------------
__global__ __launch_bounds__(256) void node_k(
    const float* __restrict__ nfeats, const float* __restrict__ h_neigh,
    const float* __restrict__ W, const float* __restrict__ bias,
    float* __restrict__ out)
{
    __shared__ float Xs[384][32];
    int tid = threadIdx.x;
    int n0  = blockIdx.x * 32;

    {
        int e = tid & 31;
        int n = n0 + e;
        bool valid = (n < N_NODES_C);
#pragma unroll
        for (int pass = 0; pass < 12; ++pass) {
            int kc = (tid >> 5) + pass * 8;   // 0..95
            int k  = kc * 4;
            float4 val = make_float4(0.f, 0.f, 0.f, 0.f);
            if (valid) {
                if (k < 128)
                    val = *reinterpret_cast<const float4*>(nfeats + (size_t)n * 128 + k);
                else
                    val = *reinterpret_cast<const float4*>(h_neigh + (size_t)n * 256 + (k - 128));
            }
            Xs[k + 0][e] = val.x;
            Xs[k + 1][e] = val.y;
            Xs[k + 2][e] = val.z;
            Xs[k + 3][e] = val.w;
        }
    }
    __syncthreads();

    tile_gemm_relu_store<384>(Xs, W, bias, out, n0, N_NODES_C);
}

// ---------------------------------------------------------------------------
// K3: edge update via bf16 MFMA. C[128 e x 128 n] = relu(X @ W^T + b),
// X = concat(h[u],h[v]) gathered+converted to bf16 in staging. BK=64.
// LDS tiles XOR-swizzled: byte ^= (row&7)<<4 (row stride 128B -> G4 fix).
// ---------------------------------------------------------------------------
__device__ __forceinline__ void stage_half_row(
    const float* __restrict__ src, char* __restrict__ lds, int row, int halfg)
{
#pragma unroll
    for (int g = 0; g < 4; ++g) {
        float4 f0 = reinterpret_cast<const float4*>(src)[g * 2 + 0];
        float4 f1 = reinterpret_cast<const float4*>(src)[g * 2 + 1];
        union { unsigned short s[8]; uint4 q; } pk;
        pk.s[0] = f2bf(f0.x); pk.s[1] = f2bf(f0.y);
        pk.s[2] = f2bf(f0.z); pk.s[3] = f2bf(f0.w);
        pk.s[4] = f2bf(f1.x); pk.s[5] = f2bf(f1.y);
        pk.s[6] = f2bf(f1.z); pk.s[7] = f2bf(f1.w);
        int byteoff = ((halfg * 4 + g) * 16) ^ ((row & 7) << 4);
        *reinterpret_cast<uint4*>(lds + row * 128 + byteoff) = pk.q;
    }
}

__global__ __launch_bounds__(256) void edge_k(
    const float* __restrict__ h, const int* __restrict__ u,
    const int* __restrict__ v, const float* __restrict__ W,
    const float* __restrict__ bias, float* __restrict__ out)
{
    __shared__ uint4 XsBuf[1024];   // 16 KB : X tile [128 rows][64 k] bf16, swizzled
    __shared__ uint4 WsBuf[1024];   // 16 KB : W tile [128 out][64 k] bf16, swizzled
    __shared__ int us[128], vs[128];
    char* Xs = (char*)XsBuf;
    char* Ws = (char*)WsBuf;

    int tid = threadIdx.x;
    int e0  = blockIdx.x * 128;
    if (tid < 128) us[tid]       = u[e0 + tid];
    else           vs[tid - 128] = v[e0 + tid - 128];
    __syncthreads();

    int wave = tid >> 6, lane = tid & 63;
    int wm = wave >> 1, wn = wave & 1;
    int srow = tid >> 1, shalf = tid & 1;

    f32x4 acc[4][4];
#pragma unroll
    for (int i = 0; i < 4; ++i)
#pragma unroll
        for (int j = 0; j < 4; ++j) acc[i][j] = (f32x4)0.f;

    for (int k0 = 0; k0 < 256; k0 += 64) {
        // ---- stage X (gather h rows, fp32->bf16) and W ----
        {
            int node = (k0 < 128) ? us[srow] : vs[srow];
            const float* xsrc = h + (size_t)node * 128 + (k0 & 127) + shalf * 32;
            stage_half_row(xsrc, Xs, srow, shalf);
            const float* wsrc = W + (size_t)srow * 256 + k0 + shalf * 32;
            stage_half_row(wsrc, Ws, srow, shalf);
        }
        __syncthreads();

        // ---- MFMA: 2 k-chunks of 32 ----
#pragma unroll
        for (int c = 0; c < 2; ++c) {
            int kb = c * 64 + (lane >> 4) * 16;   // byte offset in row
            bf16x8 a[4], b[4];
#pragma unroll
            for (int i = 0; i < 4; ++i) {
                int row = wm * 64 + i * 16 + (lane & 15);
                a[i] = *reinterpret_cast<const bf16x8*>(
                    Xs + row * 128 + (kb ^ ((row & 7) << 4)));
            }
#pragma unroll
            for (int j = 0; j < 4; ++j) {
                int row = wn * 64 + j * 16 + (lane & 15);
                b[j] = *reinterpret_cast<const bf16x8*>(
                    Ws + row * 128 + (kb ^ ((row & 7) << 4)));
            }
#pragma unroll
            for (int i = 0; i < 4; ++i)
#pragma unroll
                for (int j = 0; j < 4; ++j)
                    acc[i][j] = __builtin_amdgcn_mfma_f32_16x16x32_bf16(
                        a[i], b[j], acc[i][j], 0, 0, 0);
        }
        __syncthreads();
    }

    // ---- epilogue: bias + relu + store (C/D: col=lane&15, row=(lane>>4)*4+r) ----
    int col0 = wn * 64 + (lane & 15);
    int row0 = e0 + wm * 64 + (lane >> 4) * 4;
#pragma unroll
    for (int j = 0; j < 4; ++j) {
        float bj = bias[col0 + j * 16];
#pragma unroll
        for (int i = 0; i < 4; ++i) {
#pragma unroll
            for (int r = 0; r < 4; ++r) {
                float val = fmaxf(acc[i][j][r] + bj, 0.f);
                out[(size_t)(row0 + i * 16 + r) * 128 + col0 + j * 16] = val;
            }
        }
    }
}

// ---------------------------------------------------------------------------
extern "C" void kernel_launch(void* const* d_in, const int* in_sizes, int n_in,
                              void* d_out, int out_size, void* d_ws, size_t ws_size,
                              hipStream_t stream)
{
    const float* nfeats    = (const float*)d_in[0];
    const float* efeats    = (const float*)d_in[1];
    const int*   u         = (const int*)d_in[2];
    const int*   v         = (const int*)d_in[3];
    const float* W_apply_w = (const float*)d_in[4];
    const float* W_apply_b = (const float*)d_in[5];
    const float* W_edge_w  = (const float*)d_in[6];
    const float* W_edge_b  = (const float*)d_in[7];

    float* out      = (float*)d_out;
    float* h_nodes  = out;                                // [50000][128]
    float* edge_out = out + (size_t)N_NODES_C * 128;      // [800000][128]

    // Scratch overlays the edge-output region (409.6 MB; we use ~61 MB).
    // All scratch consumers finish before edge_k overwrites the region.
    float* scratch = edge_out;
    float* h_neigh = scratch;                              // 12.8M floats
    int*   cnt     = (int*)(scratch + 12800000);           // 50000
    int*   rowst   = cnt + N_NODES_C;                      // 50001
    int*   cursor  = rowst + N_NODES_C + 1;                // 50000
    int2*  pairs   = (int2*)(cursor + N_NODES_C + 2);      // 800000 int2 (8B align ok: offset even)

    hipMemsetAsync(cnt, 0, N_NODES_C * sizeof(int), stream);

    count_k<<<N_EDGES_C / 256, 256, 0, stream>>>(v, cnt);
    scan_k<<<1, 1024, 0, stream>>>(cnt, rowst, cursor);
    fill_k<<<N_EDGES_C / 256, 256, 0, stream>>>(v, u, cursor, pairs);
    aggregate_k<<<N_NODES_C, 256, 0, stream>>>(pairs, rowst, nfeats, efeats, h_neigh);

    node_k<<<(N_NODES_C + 31) / 32, 256, 0, stream>>>(
        nfeats, h_neigh, W_apply_w, W_apply_b, h_nodes);

    edge_k<<<N_EDGES_C / 128, 256, 0, stream>>>(
        h_nodes, u, v, W_edge_w, W_edge_b, edge_out);
}

// Round 4
// 686.687 us; speedup vs baseline: 8.7358x; 1.3144x over previous
//
#include <hip/hip_runtime.h>
#include <hip/hip_bf16.h>

#define N_NODES_C 50000
#define N_EDGES_C 800000

typedef __attribute__((ext_vector_type(8))) short bf16x8;
typedef __attribute__((ext_vector_type(4))) float f32x4;

__device__ __forceinline__ unsigned short f2bf(float f) {
    unsigned int x = __float_as_uint(f);
    unsigned int r = x + 0x7fffu + ((x >> 16) & 1u);   // RNE
    return (unsigned short)(r >> 16);
}

// ---------------------------------------------------------------------------
// CSR build: count -> scan -> fill (fill stores (edge_id, u[edge]) pairs to
// remove the eids->u dependent-load chain in aggregation).
// ---------------------------------------------------------------------------
__global__ __launch_bounds__(256) void count_k(const int* __restrict__ v, int* __restrict__ cnt)
{
    int e = blockIdx.x * 256 + threadIdx.x;   // grid sized exactly
    atomicAdd(&cnt[v[e]], 1);
}

__global__ __launch_bounds__(1024) void scan_k(const int* __restrict__ cnt,
                                               int* __restrict__ rowst,
                                               int* __restrict__ cursor)
{
    __shared__ int wsum[16];
    int tid = threadIdx.x, lane = tid & 63, wid = tid >> 6;
    int carry = 0;
    for (int base = 0; base < N_NODES_C; base += 1024) {
        int i = base + tid;
        int x = (i < N_NODES_C) ? cnt[i] : 0;
        int s = x;
#pragma unroll
        for (int d = 1; d < 64; d <<= 1) {
            int t = __shfl_up(s, d, 64);
            if (lane >= d) s += t;
        }
        if (lane == 63) wsum[wid] = s;
        __syncthreads();
        if (wid == 0) {
            int w = (lane < 16) ? wsum[lane] : 0;
#pragma unroll
            for (int d = 1; d < 16; d <<= 1) {
                int t = __shfl_up(w, d, 64);
                if (lane >= d) w += t;
            }
            if (lane < 16) wsum[lane] = w;
        }
        __syncthreads();
        int offset = carry + (wid > 0 ? wsum[wid - 1] : 0);
        int excl = offset + s - x;
        if (i < N_NODES_C) { rowst[i] = excl; cursor[i] = excl; }
        carry += wsum[15];
        __syncthreads();
    }
    if (tid == 0) rowst[N_NODES_C] = carry;
}

__global__ __launch_bounds__(256) void fill_k(const int* __restrict__ v,
                                              const int* __restrict__ u,
                                              int* __restrict__ cursor,
                                              int2* __restrict__ pairs)
{
    int e = blockIdx.x * 256 + threadIdx.x;
    int pos = atomicAdd(&cursor[v[e]], 1);
    pairs[pos] = make_int2(e, u[e]);
}

// ---------------------------------------------------------------------------
// Aggregate: one block per dst node. 4 edge-groups of 64 lanes each process
// 4 edges per iteration; each lane loads one float4 (lane<32 -> nfeats[u],
// lane>=32 -> efeats[e]). Cross-group reduce in LDS, mean, store.
// ---------------------------------------------------------------------------
__global__ __launch_bounds__(256) void aggregate_k(
    const int2* __restrict__ pairs, const int* __restrict__ rowst,
    const float* __restrict__ nfeats, const float* __restrict__ efeats,
    float* __restrict__ h_neigh)
{
    __shared__ float4 red[256];
    int n = blockIdx.x, tid = threadIdx.x;
    int grp = tid >> 6, lane = tid & 63;
    int s = rowst[n], e_end = rowst[n + 1];
    int deg = e_end - s;

    float4 acc = make_float4(0.f, 0.f, 0.f, 0.f);
    for (int i = s + grp; i < e_end; i += 4) {
        int2 p = pairs[i];                  // (edge, src node)
        const float* src = (lane < 32)
            ? (nfeats + (size_t)p.y * 128 + lane * 4)
            : (efeats + (size_t)p.x * 128 + (lane - 32) * 4);
        float4 vv = *reinterpret_cast<const float4*>(src);
        acc.x += vv.x; acc.y += vv.y; acc.z += vv.z; acc.w += vv.w;
    }
    red[tid] = acc;
    __syncthreads();
    if (grp == 0) {
        float4 a = red[lane], b = red[64 + lane], c = red[128 + lane], d = red[192 + lane];
        float r = (deg > 0) ? 1.f / (float)deg : 0.f;
        float4 o;
        o.x = (a.x + b.x + c.x + d.x) * r;
        o.y = (a.y + b.y + c.y + d.y) * r;
        o.z = (a.z + b.z + c.z + d.z) * r;
        o.w = (a.w + b.w + c.w + d.w) * r;
        *reinterpret_cast<float4*>(h_neigh + (size_t)n * 256 + lane * 4) = o;
    }
}

// ---------------------------------------------------------------------------
// Shared bf16-MFMA tile machinery. LDS tiles [128 rows][64 k] bf16, XOR
// swizzle byte ^= (row&7)<<4 (row stride 128B). stage_half_row converts
// 32 fp32 -> 32 bf16 and writes 4 swizzled uint4s.
// ---------------------------------------------------------------------------
__device__ __forceinline__ void stage_half_row(
    const float* __restrict__ src, char* __restrict__ lds, int row, int halfg)
{
#pragma unroll
    for (int g = 0; g < 4; ++g) {
        float4 f0 = reinterpret_cast<const float4*>(src)[g * 2 + 0];
        float4 f1 = reinterpret_cast<const float4*>(src)[g * 2 + 1];
        union { unsigned short s[8]; uint4 q; } pk;
        pk.s[0] = f2bf(f0.x); pk.s[1] = f2bf(f0.y);
        pk.s[2] = f2bf(f0.z); pk.s[3] = f2bf(f0.w);
        pk.s[4] = f2bf(f1.x); pk.s[5] = f2bf(f1.y);
        pk.s[6] = f2bf(f1.z); pk.s[7] = f2bf(f1.w);
        int byteoff = ((halfg * 4 + g) * 16) ^ ((row & 7) << 4);
        *reinterpret_cast<uint4*>(lds + row * 128 + byteoff) = pk.q;
    }
}

// MFMA on one staged k-slab (64 k): 2 chunks x 16 mfma, acc[4][4].
__device__ __forceinline__ void mfma_slab(
    const char* __restrict__ Xs, const char* __restrict__ Ws,
    int wm, int wn, int lane, f32x4 (&acc)[4][4])
{
#pragma unroll
    for (int c = 0; c < 2; ++c) {
        int kb = c * 64 + (lane >> 4) * 16;   // byte offset in row
        bf16x8 a[4], b[4];
#pragma unroll
        for (int i = 0; i < 4; ++i) {
            int row = wm * 64 + i * 16 + (lane & 15);
            a[i] = *reinterpret_cast<const bf16x8*>(
                Xs + row * 128 + (kb ^ ((row & 7) << 4)));
        }
#pragma unroll
        for (int j = 0; j < 4; ++j) {
            int row = wn * 64 + j * 16 + (lane & 15);
            b[j] = *reinterpret_cast<const bf16x8*>(
                Ws + row * 128 + (kb ^ ((row & 7) << 4)));
        }
#pragma unroll
        for (int i = 0; i < 4; ++i)
#pragma unroll
            for (int j = 0; j < 4; ++j)
                acc[i][j] = __builtin_amdgcn_mfma_f32_16x16x32_bf16(
                    a[i], b[j], acc[i][j], 0, 0, 0);
    }
}

// Epilogue: bias + relu + guarded store. C/D: col=lane&15, row=(lane>>4)*4+r.
__device__ __forceinline__ void epilogue_store(
    const f32x4 (&acc)[4][4], const float* __restrict__ bias,
    float* __restrict__ out, int row_base, int row_limit, int wm, int wn, int lane)
{
    int col0 = wn * 64 + (lane & 15);
    int row0 = row_base + wm * 64 + (lane >> 4) * 4;
#pragma unroll
    for (int j = 0; j < 4; ++j) {
        float bj = bias[col0 + j * 16];
#pragma unroll
        for (int i = 0; i < 4; ++i) {
#pragma unroll
            for (int r = 0; r < 4; ++r) {
                int row = row0 + i * 16 + r;
                if (row < row_limit) {
                    float val = fmaxf(acc[i][j][r] + bj, 0.f);
                    out[(size_t)row * 128 + col0 + j * 16] = val;
                }
            }
        }
    }
}

// ---------------------------------------------------------------------------
// K2: node update via bf16 MFMA. C[128 n x 128 out] = relu(X @ W^T + b),
// X = concat(nfeats[n] (128), h_neigh[n] (256)), K=384, 6 slabs of 64.
// ---------------------------------------------------------------------------
__global__ __launch_bounds__(256) void node_k(
    const float* __restrict__ nfeats, const float* __restrict__ h_neigh,
    const float* __restrict__ W, const float* __restrict__ bias,
    float* __restrict__ out)
{
    __shared__ uint4 XsBuf[1024];   // 16 KB
    __shared__ uint4 WsBuf[1024];   // 16 KB
    char* Xs = (char*)XsBuf;
    char* Ws = (char*)WsBuf;

    int tid = threadIdx.x;
    int n0  = blockIdx.x * 128;
    int wave = tid >> 6, lane = tid & 63;
    int wm = wave >> 1, wn = wave & 1;
    int srow = tid >> 1, shalf = tid & 1;

    int nrow = n0 + srow;
    if (nrow >= N_NODES_C) nrow = N_NODES_C - 1;   // clamp; store guarded

    f32x4 acc[4][4];
#pragma unroll
    for (int i = 0; i < 4; ++i)
#pragma unroll
        for (int j = 0; j < 4; ++j) acc[i][j] = (f32x4)0.f;

#pragma unroll
    for (int k0 = 0; k0 < 384; k0 += 64) {
        const float* xsrc = (k0 < 128)
            ? (nfeats  + (size_t)nrow * 128 + k0         + shalf * 32)
            : (h_neigh + (size_t)nrow * 256 + (k0 - 128) + shalf * 32);
        stage_half_row(xsrc, Xs, srow, shalf);
        const float* wsrc = W + (size_t)srow * 384 + k0 + shalf * 32;
        stage_half_row(wsrc, Ws, srow, shalf);
        __syncthreads();
        mfma_slab(Xs, Ws, wm, wn, lane, acc);
        __syncthreads();
    }

    epilogue_store(acc, bias, out, n0, N_NODES_C, wm, wn, lane);
}

// ---------------------------------------------------------------------------
// K3: edge update via bf16 MFMA. C[128 e x 128 n] = relu(X @ W^T + b),
// X = concat(h[u],h[v]) gathered+converted to bf16 in staging. K=256.
// ---------------------------------------------------------------------------
__global__ __launch_bounds__(256) void edge_k(
    const float* __restrict__ h, const int* __restrict__ u,
    const int* __restrict__ v, const float* __restrict__ W,
    const float* __restrict__ bias, float* __restrict__ out)
{
    __shared__ uint4 XsBuf[1024];   // 16 KB
    __shared__ uint4 WsBuf[1024];   // 16 KB
    __shared__ int us[128], vs[128];
    char* Xs = (char*)XsBuf;
    char* Ws = (char*)WsBuf;

    int tid = threadIdx.x;
    int e0  = blockIdx.x * 128;
    if (tid < 128) us[tid]       = u[e0 + tid];
    else           vs[tid - 128] = v[e0 + tid - 128];
    __syncthreads();

    int wave = tid >> 6, lane = tid & 63;
    int wm = wave >> 1, wn = wave & 1;
    int srow = tid >> 1, shalf = tid & 1;

    f32x4 acc[4][4];
#pragma unroll
    for (int i = 0; i < 4; ++i)
#pragma unroll
        for (int j = 0; j < 4; ++j) acc[i][j] = (f32x4)0.f;

#pragma unroll
    for (int k0 = 0; k0 < 256; k0 += 64) {
        int node = (k0 < 128) ? us[srow] : vs[srow];
        const float* xsrc = h + (size_t)node * 128 + (k0 & 127) + shalf * 32;
        stage_half_row(xsrc, Xs, srow, shalf);
        const float* wsrc = W + (size_t)srow * 256 + k0 + shalf * 32;
        stage_half_row(wsrc, Ws, srow, shalf);
        __syncthreads();
        mfma_slab(Xs, Ws, wm, wn, lane, acc);
        __syncthreads();
    }

    epilogue_store(acc, bias, out, e0, N_EDGES_C, wm, wn, lane);
}

// ---------------------------------------------------------------------------
extern "C" void kernel_launch(void* const* d_in, const int* in_sizes, int n_in,
                              void* d_out, int out_size, void* d_ws, size_t ws_size,
                              hipStream_t stream)
{
    const float* nfeats    = (const float*)d_in[0];
    const float* efeats    = (const float*)d_in[1];
    const int*   u         = (const int*)d_in[2];
    const int*   v         = (const int*)d_in[3];
    const float* W_apply_w = (const float*)d_in[4];
    const float* W_apply_b = (const float*)d_in[5];
    const float* W_edge_w  = (const float*)d_in[6];
    const float* W_edge_b  = (const float*)d_in[7];

    float* out      = (float*)d_out;
    float* h_nodes  = out;                                // [50000][128]
    float* edge_out = out + (size_t)N_NODES_C * 128;      // [800000][128]

    // Scratch overlays the edge-output region (409.6 MB; we use ~61 MB).
    // All scratch consumers finish before edge_k overwrites the region.
    float* scratch = edge_out;
    float* h_neigh = scratch;                              // 12.8M floats
    int*   cnt     = (int*)(scratch + 12800000);           // 50000
    int*   rowst   = cnt + N_NODES_C;                      // 50001
    int*   cursor  = rowst + N_NODES_C + 1;                // 50000
    int2*  pairs   = (int2*)(cursor + N_NODES_C + 2);      // 800000 int2

    hipMemsetAsync(cnt, 0, N_NODES_C * sizeof(int), stream);

    count_k<<<N_EDGES_C / 256, 256, 0, stream>>>(v, cnt);
    scan_k<<<1, 1024, 0, stream>>>(cnt, rowst, cursor);
    fill_k<<<N_EDGES_C / 256, 256, 0, stream>>>(v, u, cursor, pairs);
    aggregate_k<<<N_NODES_C, 256, 0, stream>>>(pairs, rowst, nfeats, efeats, h_neigh);

    node_k<<<(N_NODES_C + 127) / 128, 256, 0, stream>>>(
        nfeats, h_neigh, W_apply_w, W_apply_b, h_nodes);

    edge_k<<<N_EDGES_C / 128, 256, 0, stream>>>(
        h_nodes, u, v, W_edge_w, W_edge_b, edge_out);
}